// Round 4
// baseline (284.815 us; speedup 1.0000x reference)
//
#include <hip/hip_runtime.h>
#include <math.h>

// Problem constants
#define BB 8
#define HH 1024
#define WW 1024
#define HW (1024*1024)

#define TW 128        // tile width (output px)
#define TH 16         // tile height
#define HALO_H (TH+6) // 22
#define TSTRIDE 136   // tile row stride (bytes); stored col s holds gx = x0-4+s,
                      // so center px gx=x0+x sits at stored col x+4 (u32-aligned)
#define NCHUNK (HALO_H*34)  // 748 int4 chunks of target halo
#define NCOPY 64      // atomic accumulator copies
#define CSTRIDE 64    // doubles per copy region (54 used, pad to 64 = 512 B)
#define NSLOT 18      // per image: [0]=focal, [1]=edge, [2+b]=I_b, [10+b]=U_b
// acc layout (copy-major: each copy owns a 512 B region -> no cross-XCD
// false sharing; WRITE_SIZE dropped 17.9 MB -> 1.1 MB with this):
//   acc[copy*CSTRIDE + img*NSLOT + slot]

// Pin a float4's components in registers: ties each scalar lane as an asm
// output so the compiler cannot rematerialize/sink the producing load.
// (Whole-float4 "+v" fails: "tied indirect register inputs" on gfx950.)
__device__ __forceinline__ void pin4(float4& v) {
    asm volatile("" : "+v"(v.x), "+v"(v.y), "+v"(v.z), "+v"(v.w));
}

__global__ __launch_bounds__(256, 8)
void loss_main(const float* __restrict__ pred,
               const float* __restrict__ diss,
               const int*   __restrict__ target,
               double*      __restrict__ acc)
{
    // target/count data is in {0..29}: stored as bytes, ~8.8 KB LDS total.
    __shared__ __align__(16) unsigned char tile[HALO_H][TSTRIDE]; // 2992 B
    __shared__ __align__(16) unsigned char h5[HALO_H][TW];        // 2816 B
    __shared__ __align__(16) unsigned char h7[HALO_H][TW];        // 2816 B
    __shared__ float red[4][12];

    const int bx = blockIdx.x;   // 0..7
    const int by = blockIdx.y;   // 0..63
    const int b  = blockIdx.z;   // 0..7
    const int x0 = bx * TW, y0 = by * TH;
    const int tid = threadIdx.x;       // 0..255
    const int txx = tid & 31;          // x-group (4 px each)
    const int ty  = tid >> 5;          // 0..7

    // ---- stage 0: issue ALL 12 stage-3 float4 loads up front ----
    // Round-2 lesson: without hard pinning the compiler remats/sinks these
    // (VGPR_Count=36 proved it), leaving MLP=1 per wave -> 2.3 TB/s ceiling.
    const float* p00 = pred + ((size_t)(0 * BB + b) * 2 + 0) * HW;
    const float* p01 = p00 + HW;
    const float* p10 = pred + ((size_t)(1 * BB + b) * 2 + 0) * HW;
    const float* p11 = p10 + HW;
    const float* q0  = diss + ((size_t)b * 2 + 0) * HW;
    const float* q1  = q0 + HW;

    const int x  = txx * 4;
    const int gx = x0 + x;
    const size_t offA = (size_t)(y0 + ty) * WW + gx;       // k=0 row
    const size_t offB = offA + (size_t)8 * WW;             // k=1 row

    float4 v00a = *(const float4*)(p00 + offA);
    float4 v01a = *(const float4*)(p01 + offA);
    float4 v10a = *(const float4*)(p10 + offA);
    float4 v11a = *(const float4*)(p11 + offA);
    float4 w0a  = *(const float4*)(q0  + offA);
    float4 w1a  = *(const float4*)(q1  + offA);
    float4 v00b = *(const float4*)(p00 + offB);
    float4 v01b = *(const float4*)(p01 + offB);
    float4 v10b = *(const float4*)(p10 + offB);
    float4 v11b = *(const float4*)(p11 + offB);
    float4 w0b  = *(const float4*)(q0  + offB);
    float4 w1b  = *(const float4*)(q1  + offB);
    __builtin_amdgcn_sched_barrier(0);   // pin the 12 loads at kernel entry

    // ---- stage 1: target halo -> LDS bytes, batch-issued loads ----
    // All 3 chunk loads use clamped (always in-bounds) addresses and issue
    // back-to-back; packing + ds_write happen after, so the 3 loads overlap.
    const int* tgt_b = target + (size_t)b * HW;
    int4 iv[3]; int rr[3], mm[3];
    bool act[3], mainp[3], rowin[3];
    #pragma unroll
    for (int i = 0; i < 3; ++i) {
        const int ch = tid + 256 * i;
        const bool a = ch < NCHUNK;
        const int chc = a ? ch : 0;
        const int r = chc / 34;
        const int m = chc - r * 34;
        const int gy  = y0 - 3 + r;
        const int gxb = x0 - 4 + 4 * m;
        const bool ri = (gy >= 0) && (gy < HH);
        const bool fp = a && ri && (gxb >= 0) && (gxb + 3 < WW);
        act[i] = a; rr[i] = r; mm[i] = m; rowin[i] = ri; mainp[i] = fp;
        const int gyc  = ri ? gy  : 0;
        const int gxbc = fp ? gxb : 0;
        iv[i] = *(const int4*)(tgt_b + (size_t)gyc * WW + gxbc); // always safe
    }
    #pragma unroll
    for (int i = 0; i < 3; ++i) {
        if (!act[i]) continue;
        unsigned v = 0u;
        if (mainp[i]) {
            v = (unsigned)(iv[i].x & 0xff)
              | ((unsigned)(iv[i].y & 0xff) << 8)
              | ((unsigned)(iv[i].z & 0xff) << 16)
              | ((unsigned)(iv[i].w & 0xff) << 24);
        } else if (rowin[i]) {
            const int gy  = y0 - 3 + rr[i];
            const int gxb = x0 - 4 + 4 * mm[i];
            #pragma unroll
            for (int j = 0; j < 4; ++j) {
                const int gxj = gxb + j;
                if (gxj >= 0 && gxj < WW)
                    v |= (unsigned)(tgt_b[(size_t)gy * WW + gxj] & 0xff) << (8 * j);
            }
        }
        *(unsigned*)&tile[rr[i]][4 * mm[i]] = v;
    }

    // Hard-pin the prefetched values so their loads stay hoisted above the
    // barrier; the implied vmcnt wait merges with stage 1's own drain.
    pin4(v00a); pin4(v01a); pin4(v10a); pin4(v11a); pin4(w0a); pin4(w1a);
    pin4(v00b); pin4(v01b); pin4(v10b); pin4(v11b); pin4(w0b); pin4(w1b);
    __syncthreads();

    // ---- stage 2: horizontal sums, SWAR on packed bytes (max 7 < 256) ----
    // h5[r][x] = stored cols x+2..x+6 ; h7[r][x] = stored cols x+1..x+7
    for (int g = tid; g < HALO_H * 32; g += 256) {
        int r  = g >> 5;
        int xg = (g & 31) << 2;
        unsigned c0 = *(const unsigned*)&tile[r][xg];       // stored x..x+3
        unsigned c1 = *(const unsigned*)&tile[r][xg + 4];   // x+4..x+7
        unsigned c2 = *(const unsigned*)&tile[r][xg + 8];   // x+8..x+11
        unsigned A1 = (c0 >> 8)  | (c1 << 24);  // P(x+1)
        unsigned A2 = (c0 >> 16) | (c1 << 16);  // P(x+2)
        unsigned A3 = (c0 >> 24) | (c1 << 8);   // P(x+3)
        unsigned A5 = (c1 >> 8)  | (c2 << 24);  // P(x+5)
        unsigned A6 = (c1 >> 16) | (c2 << 16);  // P(x+6)
        unsigned A7 = (c1 >> 24) | (c2 << 8);   // P(x+7)
        unsigned v5 = A2 + A3 + c1 + A5 + A6;   // bytes <= 5
        unsigned v7 = v5 + A1 + A7;             // bytes <= 7
        *(unsigned*)&h5[r][xg] = v5;
        *(unsigned*)&h7[r][xg] = v7;
    }
    __syncthreads();

    // ---- stage 3: fused per-pixel terms on pinned prefetched data ----
    float sf0=0.f, se0=0.f, si0=0.f, sp0=0.f;   // sp = sum of p1
    float sf1=0.f, se1=0.f, si1=0.f, sp1=0.f;
    float sf2=0.f, se2=0.f, si2=0.f, sd1=0.f;   // sd1 = sum of d1
    float st = 0.f;                             // sum of t (shared U part)

    const unsigned t4a   = *(const unsigned*)&tile[ty + 3][x + 4];
    const unsigned cnt4a = *(const unsigned*)&tile[ty    ][x + 4]
                         + *(const unsigned*)&tile[ty + 6][x + 4]
                         + *(const unsigned*)&h5[ty + 1][x]
                         + *(const unsigned*)&h5[ty + 2][x]
                         + *(const unsigned*)&h7[ty + 3][x]
                         + *(const unsigned*)&h5[ty + 4][x]
                         + *(const unsigned*)&h5[ty + 5][x];
    const unsigned t4b   = *(const unsigned*)&tile[ty + 11][x + 4];
    const unsigned cnt4b = *(const unsigned*)&tile[ty +  8][x + 4]
                         + *(const unsigned*)&tile[ty + 14][x + 4]
                         + *(const unsigned*)&h5[ty +  9][x]
                         + *(const unsigned*)&h5[ty + 10][x]
                         + *(const unsigned*)&h7[ty + 11][x]
                         + *(const unsigned*)&h5[ty + 12][x]
                         + *(const unsigned*)&h5[ty + 13][x];

    auto half = [&](unsigned t4, unsigned cnt4,
                    const float4& v00, const float4& v01,
                    const float4& v10, const float4& v11,
                    const float4& w0,  const float4& w1) {
        #pragma unroll
        for (int j = 0; j < 4; ++j) {
            const unsigned tb = (t4 >> (8 * j)) & 0xffu;
            const float t  = (float)tb;
            const float at = fabsf(t - (float)((cnt4 >> (8 * j)) & 0xffu) * (1.0f / 29.0f));
            st += t;
            {   // image 0 (softmax of 2 channels)
                float a0 = ((const float*)&v00)[j], a1 = ((const float*)&v01)[j];
                float p1v = __builtin_amdgcn_rcpf(1.0f + __expf(a0 - a1));
                float pt  = (tb != 0u) ? p1v : 1.0f - p1v;
                float lp  = __logf(pt + 1e-10f);
                sf0 -= lp; se0 -= lp * at; si0 += p1v * t; sp0 += p1v;
            }
            {   // image 1
                float a0 = ((const float*)&v10)[j], a1 = ((const float*)&v11)[j];
                float p1v = __builtin_amdgcn_rcpf(1.0f + __expf(a0 - a1));
                float pt  = (tb != 0u) ? p1v : 1.0f - p1v;
                float lp  = __logf(pt + 1e-10f);
                sf1 -= lp; se1 -= lp * at; si1 += p1v * t; sp1 += p1v;
            }
            {   // Diss (raw probs)
                float d0 = ((const float*)&w0)[j], d1 = ((const float*)&w1)[j];
                float pt = (tb != 0u) ? d1 : d0;
                float lp = __logf(pt + 1e-10f);
                sf2 -= lp; se2 -= lp * at; si2 += d1 * t; sd1 += d1;
            }
        }
    };
    half(t4a, cnt4a, v00a, v01a, v10a, v11a, w0a, w1a);
    half(t4b, cnt4b, v00b, v01b, v10b, v11b, w0b, w1b);

    // ---- stage 4: block reduction -> 12 f64 atomics ----
    float vals[12] = {sf0,se0,si0,sp0+st, sf1,se1,si1,sp1+st, sf2,se2,si2,sd1+st};
    #pragma unroll
    for (int j = 0; j < 12; ++j) {
        float v = vals[j];
        #pragma unroll
        for (int s = 32; s > 0; s >>= 1) v += __shfl_down(v, s, 64);
        vals[j] = v;
    }
    const int wave = tid >> 6;
    const int lane = tid & 63;
    if (lane == 0) {
        #pragma unroll
        for (int j = 0; j < 12; ++j) red[wave][j] = vals[j];
    }
    __syncthreads();
    if (tid < 12) {
        double s = (double)red[0][tid] + (double)red[1][tid]
                 + (double)red[2][tid] + (double)red[3][tid];
        const int img  = tid >> 2;
        const int what = tid & 3;
        int slot;
        if      (what == 0) slot = 0;
        else if (what == 1) slot = 1;
        else if (what == 2) slot = 2 + b;
        else                slot = 10 + b;
        const int copy = (by * 8 + bx) & (NCOPY - 1);
        unsafeAtomicAdd(acc + (size_t)copy * CSTRIDE + (img * NSLOT + slot), s);
    }
}

__global__ __launch_bounds__(256)
void finalize_kernel(const double* __restrict__ acc,
                     const float*  __restrict__ diff,
                     const float*  __restrict__ sigma,
                     float*        __restrict__ out)
{
    __shared__ double ssum[54];
    const int t = threadIdx.x;
    if (t < 216) {
        const int slot_lin = t >> 2;   // 0..53 = img*18+slot
        const int part     = t & 3;    // 16 copies each
        const double* p = acc + slot_lin + (size_t)part * 16 * CSTRIDE;
        double s = 0.0;
        #pragma unroll
        for (int j = 0; j < 16; ++j) s += p[(size_t)j * CSTRIDE];
        s += __shfl_down(s, 1, 64);
        s += __shfl_down(s, 2, 64);
        if (part == 0) ssum[slot_lin] = s;
    }
    __syncthreads();
    if (t == 0) {
        const double sig0 = (double)sigma[0] * (double)sigma[0];
        const double sig1 = (double)sigma[1] * (double)sigma[1];
        const double sig2 = (double)sigma[2] * (double)sigma[2];
        const double inv  = 1.0 / (double)((size_t)BB * HW);
        double loss = 0.0;
        for (int i = 0; i < 3; ++i) {
            const double* A = ssum + i * NSLOT;
            double focal = A[0] * inv;
            double edge  = A[1] * inv;
            double dsum  = 0.0;
            for (int b = 0; b < BB; ++b)
                dsum += 2.0 * A[2 + b] / (A[10 + b] + 1e-10);
            double dice = 1.0 - dsum / (double)BB;
            loss += focal / sig0 + dice / sig1 + edge / sig2;
        }
        loss += (double)diff[0];
        loss += 0.5 * (log(sig0) + log(sig1) + log(sig2));
        out[0] = (float)loss;
    }
}

extern "C" void kernel_launch(void* const* d_in, const int* in_sizes, int n_in,
                              void* d_out, int out_size, void* d_ws, size_t ws_size,
                              hipStream_t stream)
{
    const float* pred   = (const float*)d_in[0]; // (2,8,2,1024,1024)
    const float* diss   = (const float*)d_in[1]; // (1,8,2,1024,1024)
    const int*   target = (const int*)  d_in[2]; // (8,1024,1024)
    const float* diff   = (const float*)d_in[3];
    const float* sigma  = (const float*)d_in[4];
    double* acc = (double*)d_ws;

    (void)hipMemsetAsync(d_ws, 0, (size_t)NCOPY * CSTRIDE * sizeof(double), stream);

    dim3 grid(WW / TW, HH / TH, BB);   // (8, 64, 8)
    loss_main<<<grid, 256, 0, stream>>>(pred, diss, target, acc);
    finalize_kernel<<<1, 256, 0, stream>>>(acc, diff, sigma, (float*)d_out);
}

// Round 5
// 268.544 us; speedup vs baseline: 1.0606x; 1.0606x over previous
//
#include <hip/hip_runtime.h>
#include <math.h>

// Problem constants
#define BB 8
#define HH 1024
#define WW 1024
#define HW (1024*1024)

#define TW 128        // tile width (output px)
#define TH 16         // tile height
#define HALO_H (TH+6) // 22
#define TSTRIDE 136   // tile row stride (bytes); stored col s holds gx = x0-4+s,
                      // so center px gx=x0+x sits at stored col x+4 (u32-aligned)
#define NCHUNK (HALO_H*34)  // 748 int4 chunks of target halo
#define NCOPY 64      // atomic accumulator copies
#define CSTRIDE 64    // doubles per copy region (54 used, pad to 64 = 512 B)
#define NSLOT 18      // per image: [0]=focal, [1]=edge, [2+b]=I_b, [10+b]=U_b
// acc layout (copy-major: each copy owns a 512 B region -> no cross-XCD
// false sharing; WRITE_SIZE dropped 17.9 MB -> 1.1 MB with this):
//   acc[copy*CSTRIDE + img*NSLOT + slot]

// Pin a float4's components in registers: ties each scalar lane as an asm
// output so the compiler cannot rematerialize/sink the producing load.
// (Whole-float4 "+v" fails: "tied indirect register inputs" on gfx950.)
__device__ __forceinline__ void pin4(float4& v) {
    asm volatile("" : "+v"(v.x), "+v"(v.y), "+v"(v.z), "+v"(v.w));
}

// Round-4 lesson: (256,8) caps VGPR at 64 -> the 48-VGPR pinned payload
// SPILLED TO SCRATCH (WRITE_SIZE 1 MB -> 118.7 MB, +10 us). (256,4) allows
// 128 VGPRs; 4 waves/SIMD still fully covers latency (15 KB in flight/wave).
__global__ __launch_bounds__(256, 4)
void loss_main(const float* __restrict__ pred,
               const float* __restrict__ diss,
               const int*   __restrict__ target,
               double*      __restrict__ acc)
{
    // target/count data is in {0..29}: stored as bytes, ~8.8 KB LDS total.
    __shared__ __align__(16) unsigned char tile[HALO_H][TSTRIDE]; // 2992 B
    __shared__ __align__(16) unsigned char h5[HALO_H][TW];        // 2816 B
    __shared__ __align__(16) unsigned char h7[HALO_H][TW];        // 2816 B
    __shared__ float red[4][12];

    const int bx = blockIdx.x;   // 0..7
    const int by = blockIdx.y;   // 0..63
    const int b  = blockIdx.z;   // 0..7
    const int x0 = bx * TW, y0 = by * TH;
    const int tid = threadIdx.x;       // 0..255
    const int txx = tid & 31;          // x-group (4 px each)
    const int ty  = tid >> 5;          // 0..7

    // ---- stage 0: issue ALL 12 stage-3 float4 loads up front ----
    // Round-2 lesson: without hard pinning the compiler remats/sinks these
    // (VGPR_Count=36 proved it), leaving MLP=1 per wave -> 2.3 TB/s ceiling.
    const float* p00 = pred + ((size_t)(0 * BB + b) * 2 + 0) * HW;
    const float* p01 = p00 + HW;
    const float* p10 = pred + ((size_t)(1 * BB + b) * 2 + 0) * HW;
    const float* p11 = p10 + HW;
    const float* q0  = diss + ((size_t)b * 2 + 0) * HW;
    const float* q1  = q0 + HW;

    const int x  = txx * 4;
    const int gx = x0 + x;
    const size_t offA = (size_t)(y0 + ty) * WW + gx;       // k=0 row
    const size_t offB = offA + (size_t)8 * WW;             // k=1 row

    float4 v00a = *(const float4*)(p00 + offA);
    float4 v01a = *(const float4*)(p01 + offA);
    float4 v10a = *(const float4*)(p10 + offA);
    float4 v11a = *(const float4*)(p11 + offA);
    float4 w0a  = *(const float4*)(q0  + offA);
    float4 w1a  = *(const float4*)(q1  + offA);
    float4 v00b = *(const float4*)(p00 + offB);
    float4 v01b = *(const float4*)(p01 + offB);
    float4 v10b = *(const float4*)(p10 + offB);
    float4 v11b = *(const float4*)(p11 + offB);
    float4 w0b  = *(const float4*)(q0  + offB);
    float4 w1b  = *(const float4*)(q1  + offB);
    __builtin_amdgcn_sched_barrier(0);   // pin the 12 loads at kernel entry

    // ---- stage 1: target halo -> LDS bytes, batch-issued loads ----
    // All 3 chunk loads use clamped (always in-bounds) addresses and issue
    // back-to-back; packing + ds_write happen after, so the 3 loads overlap.
    const int* tgt_b = target + (size_t)b * HW;
    int4 iv[3]; int rr[3], mm[3];
    bool act[3], mainp[3], rowin[3];
    #pragma unroll
    for (int i = 0; i < 3; ++i) {
        const int ch = tid + 256 * i;
        const bool a = ch < NCHUNK;
        const int chc = a ? ch : 0;
        const int r = chc / 34;
        const int m = chc - r * 34;
        const int gy  = y0 - 3 + r;
        const int gxb = x0 - 4 + 4 * m;
        const bool ri = (gy >= 0) && (gy < HH);
        const bool fp = a && ri && (gxb >= 0) && (gxb + 3 < WW);
        act[i] = a; rr[i] = r; mm[i] = m; rowin[i] = ri; mainp[i] = fp;
        const int gyc  = ri ? gy  : 0;
        const int gxbc = fp ? gxb : 0;
        iv[i] = *(const int4*)(tgt_b + (size_t)gyc * WW + gxbc); // always safe
    }
    #pragma unroll
    for (int i = 0; i < 3; ++i) {
        if (!act[i]) continue;
        unsigned v = 0u;
        if (mainp[i]) {
            v = (unsigned)(iv[i].x & 0xff)
              | ((unsigned)(iv[i].y & 0xff) << 8)
              | ((unsigned)(iv[i].z & 0xff) << 16)
              | ((unsigned)(iv[i].w & 0xff) << 24);
        } else if (rowin[i]) {
            const int gy  = y0 - 3 + rr[i];
            const int gxb = x0 - 4 + 4 * mm[i];
            #pragma unroll
            for (int j = 0; j < 4; ++j) {
                const int gxj = gxb + j;
                if (gxj >= 0 && gxj < WW)
                    v |= (unsigned)(tgt_b[(size_t)gy * WW + gxj] & 0xff) << (8 * j);
            }
        }
        *(unsigned*)&tile[rr[i]][4 * mm[i]] = v;
    }

    // Hard-pin the prefetched values so their loads stay hoisted above the
    // barrier; the implied vmcnt wait merges with stage 1's own drain.
    pin4(v00a); pin4(v01a); pin4(v10a); pin4(v11a); pin4(w0a); pin4(w1a);
    pin4(v00b); pin4(v01b); pin4(v10b); pin4(v11b); pin4(w0b); pin4(w1b);
    __syncthreads();

    // ---- stage 2: horizontal sums, SWAR on packed bytes (max 7 < 256) ----
    // h5[r][x] = stored cols x+2..x+6 ; h7[r][x] = stored cols x+1..x+7
    for (int g = tid; g < HALO_H * 32; g += 256) {
        int r  = g >> 5;
        int xg = (g & 31) << 2;
        unsigned c0 = *(const unsigned*)&tile[r][xg];       // stored x..x+3
        unsigned c1 = *(const unsigned*)&tile[r][xg + 4];   // x+4..x+7
        unsigned c2 = *(const unsigned*)&tile[r][xg + 8];   // x+8..x+11
        unsigned A1 = (c0 >> 8)  | (c1 << 24);  // P(x+1)
        unsigned A2 = (c0 >> 16) | (c1 << 16);  // P(x+2)
        unsigned A3 = (c0 >> 24) | (c1 << 8);   // P(x+3)
        unsigned A5 = (c1 >> 8)  | (c2 << 24);  // P(x+5)
        unsigned A6 = (c1 >> 16) | (c2 << 16);  // P(x+6)
        unsigned A7 = (c1 >> 24) | (c2 << 8);   // P(x+7)
        unsigned v5 = A2 + A3 + c1 + A5 + A6;   // bytes <= 5
        unsigned v7 = v5 + A1 + A7;             // bytes <= 7
        *(unsigned*)&h5[r][xg] = v5;
        *(unsigned*)&h7[r][xg] = v7;
    }
    __syncthreads();

    // ---- stage 3: fused per-pixel terms on pinned prefetched data ----
    float sf0=0.f, se0=0.f, si0=0.f, sp0=0.f;   // sp = sum of p1
    float sf1=0.f, se1=0.f, si1=0.f, sp1=0.f;
    float sf2=0.f, se2=0.f, si2=0.f, sd1=0.f;   // sd1 = sum of d1
    float st = 0.f;                             // sum of t (shared U part)

    const unsigned t4a   = *(const unsigned*)&tile[ty + 3][x + 4];
    const unsigned cnt4a = *(const unsigned*)&tile[ty    ][x + 4]
                         + *(const unsigned*)&tile[ty + 6][x + 4]
                         + *(const unsigned*)&h5[ty + 1][x]
                         + *(const unsigned*)&h5[ty + 2][x]
                         + *(const unsigned*)&h7[ty + 3][x]
                         + *(const unsigned*)&h5[ty + 4][x]
                         + *(const unsigned*)&h5[ty + 5][x];
    const unsigned t4b   = *(const unsigned*)&tile[ty + 11][x + 4];
    const unsigned cnt4b = *(const unsigned*)&tile[ty +  8][x + 4]
                         + *(const unsigned*)&tile[ty + 14][x + 4]
                         + *(const unsigned*)&h5[ty +  9][x]
                         + *(const unsigned*)&h5[ty + 10][x]
                         + *(const unsigned*)&h7[ty + 11][x]
                         + *(const unsigned*)&h5[ty + 12][x]
                         + *(const unsigned*)&h5[ty + 13][x];

    auto half = [&](unsigned t4, unsigned cnt4,
                    const float4& v00, const float4& v01,
                    const float4& v10, const float4& v11,
                    const float4& w0,  const float4& w1) {
        #pragma unroll
        for (int j = 0; j < 4; ++j) {
            const unsigned tb = (t4 >> (8 * j)) & 0xffu;
            const float t  = (float)tb;
            const float at = fabsf(t - (float)((cnt4 >> (8 * j)) & 0xffu) * (1.0f / 29.0f));
            st += t;
            {   // image 0 (softmax of 2 channels)
                float a0 = ((const float*)&v00)[j], a1 = ((const float*)&v01)[j];
                float p1v = __builtin_amdgcn_rcpf(1.0f + __expf(a0 - a1));
                float pt  = (tb != 0u) ? p1v : 1.0f - p1v;
                float lp  = __logf(pt + 1e-10f);
                sf0 -= lp; se0 -= lp * at; si0 += p1v * t; sp0 += p1v;
            }
            {   // image 1
                float a0 = ((const float*)&v10)[j], a1 = ((const float*)&v11)[j];
                float p1v = __builtin_amdgcn_rcpf(1.0f + __expf(a0 - a1));
                float pt  = (tb != 0u) ? p1v : 1.0f - p1v;
                float lp  = __logf(pt + 1e-10f);
                sf1 -= lp; se1 -= lp * at; si1 += p1v * t; sp1 += p1v;
            }
            {   // Diss (raw probs)
                float d0 = ((const float*)&w0)[j], d1 = ((const float*)&w1)[j];
                float pt = (tb != 0u) ? d1 : d0;
                float lp = __logf(pt + 1e-10f);
                sf2 -= lp; se2 -= lp * at; si2 += d1 * t; sd1 += d1;
            }
        }
    };
    half(t4a, cnt4a, v00a, v01a, v10a, v11a, w0a, w1a);
    half(t4b, cnt4b, v00b, v01b, v10b, v11b, w0b, w1b);

    // ---- stage 4: block reduction -> 12 f64 atomics ----
    float vals[12] = {sf0,se0,si0,sp0+st, sf1,se1,si1,sp1+st, sf2,se2,si2,sd1+st};
    #pragma unroll
    for (int j = 0; j < 12; ++j) {
        float v = vals[j];
        #pragma unroll
        for (int s = 32; s > 0; s >>= 1) v += __shfl_down(v, s, 64);
        vals[j] = v;
    }
    const int wave = tid >> 6;
    const int lane = tid & 63;
    if (lane == 0) {
        #pragma unroll
        for (int j = 0; j < 12; ++j) red[wave][j] = vals[j];
    }
    __syncthreads();
    if (tid < 12) {
        double s = (double)red[0][tid] + (double)red[1][tid]
                 + (double)red[2][tid] + (double)red[3][tid];
        const int img  = tid >> 2;
        const int what = tid & 3;
        int slot;
        if      (what == 0) slot = 0;
        else if (what == 1) slot = 1;
        else if (what == 2) slot = 2 + b;
        else                slot = 10 + b;
        const int copy = (by * 8 + bx) & (NCOPY - 1);
        unsafeAtomicAdd(acc + (size_t)copy * CSTRIDE + (img * NSLOT + slot), s);
    }
}

__global__ __launch_bounds__(256)
void finalize_kernel(const double* __restrict__ acc,
                     const float*  __restrict__ diff,
                     const float*  __restrict__ sigma,
                     float*        __restrict__ out)
{
    __shared__ double ssum[54];
    const int t = threadIdx.x;
    if (t < 216) {
        const int slot_lin = t >> 2;   // 0..53 = img*18+slot
        const int part     = t & 3;    // 16 copies each
        const double* p = acc + slot_lin + (size_t)part * 16 * CSTRIDE;
        double s = 0.0;
        #pragma unroll
        for (int j = 0; j < 16; ++j) s += p[(size_t)j * CSTRIDE];
        s += __shfl_down(s, 1, 64);
        s += __shfl_down(s, 2, 64);
        if (part == 0) ssum[slot_lin] = s;
    }
    __syncthreads();
    if (t == 0) {
        const double sig0 = (double)sigma[0] * (double)sigma[0];
        const double sig1 = (double)sigma[1] * (double)sigma[1];
        const double sig2 = (double)sigma[2] * (double)sigma[2];
        const double inv  = 1.0 / (double)((size_t)BB * HW);
        double loss = 0.0;
        for (int i = 0; i < 3; ++i) {
            const double* A = ssum + i * NSLOT;
            double focal = A[0] * inv;
            double edge  = A[1] * inv;
            double dsum  = 0.0;
            for (int b = 0; b < BB; ++b)
                dsum += 2.0 * A[2 + b] / (A[10 + b] + 1e-10);
            double dice = 1.0 - dsum / (double)BB;
            loss += focal / sig0 + dice / sig1 + edge / sig2;
        }
        loss += (double)diff[0];
        loss += 0.5 * (log(sig0) + log(sig1) + log(sig2));
        out[0] = (float)loss;
    }
}

extern "C" void kernel_launch(void* const* d_in, const int* in_sizes, int n_in,
                              void* d_out, int out_size, void* d_ws, size_t ws_size,
                              hipStream_t stream)
{
    const float* pred   = (const float*)d_in[0]; // (2,8,2,1024,1024)
    const float* diss   = (const float*)d_in[1]; // (1,8,2,1024,1024)
    const int*   target = (const int*)  d_in[2]; // (8,1024,1024)
    const float* diff   = (const float*)d_in[3];
    const float* sigma  = (const float*)d_in[4];
    double* acc = (double*)d_ws;

    (void)hipMemsetAsync(d_ws, 0, (size_t)NCOPY * CSTRIDE * sizeof(double), stream);

    dim3 grid(WW / TW, HH / TH, BB);   // (8, 64, 8)
    loss_main<<<grid, 256, 0, stream>>>(pred, diss, target, acc);
    finalize_kernel<<<1, 256, 0, stream>>>(acc, diff, sigma, (float*)d_out);
}

// Round 6
// 264.193 us; speedup vs baseline: 1.0781x; 1.0165x over previous
//
#include <hip/hip_runtime.h>
#include <math.h>

// Problem constants
#define BB 8
#define HH 1024
#define WW 1024
#define HW (1024*1024)

#define TW 128        // tile width (output px)
#define TH 16         // tile height
#define HALO_H (TH+6) // 22
#define TSTRIDE 136   // target tile row stride (bytes)
#define NCHUNK (HALO_H*34)  // 748 int4 chunks of target halo
#define NCOPY 64      // atomic accumulator copies
#define CSTRIDE 64    // doubles per copy region (54 used, pad to 64 = 512 B)
#define NSLOT 18      // per image: [0]=focal, [1]=edge, [2+b]=I_b, [10+b]=U_b
// acc layout (copy-major: each copy owns a 512 B region -> no cross-XCD
// false sharing; WRITE_SIZE 17.9 MB -> 1.1 MB with this):
//   acc[copy*CSTRIDE + img*NSLOT + slot]

// Rounds 2-5 lesson: VGPR-resident prefetch is un-winnable at HIP source
// level (compiler sinks (r2, VGPR=36), spills (r4, +118MB scratch), or
// interleaves the pins (r5, VGPR=40)). Switch to hardware DMA:
// global_load_lds has ZERO VGPR payload, per-lane global addr,
// wave-uniform LDS dest (lane i lands at base + i*16), and the
// __syncthreads vmcnt(0) drain is the natural completion point.
typedef const __attribute__((address_space(1))) unsigned GU;
typedef __attribute__((address_space(3))) unsigned LU;
__device__ __forceinline__ void async16(const float* g, void* lds) {
    __builtin_amdgcn_global_load_lds((GU*)g, (LU*)lds, 16, 0, 0);
}

__global__ __launch_bounds__(256)
void loss_main(const float* __restrict__ pred,
               const float* __restrict__ diss,
               const int*   __restrict__ target,
               double*      __restrict__ acc)
{
    // Six 16x128 f32 tiles staged by DMA: 48 KB. Byte tiles ~8.8 KB.
    // Total ~58 KB -> 2 blocks/CU. Latency hiding now comes from the
    // 48 KB/block in the vmem queue, not from wave count.
    __shared__ __align__(16) float planes[6][TH][TW];             // 49152 B
    __shared__ __align__(16) unsigned char tile[HALO_H][TSTRIDE]; // 2992 B
    __shared__ __align__(16) unsigned char h5[HALO_H][TW];        // 2816 B
    __shared__ __align__(16) unsigned char h7[HALO_H][TW];        // 2816 B
    __shared__ float red[4][12];

    const int bx = blockIdx.x;   // 0..7
    const int by = blockIdx.y;   // 0..63
    const int b  = blockIdx.z;   // 0..7
    const int x0 = bx * TW, y0 = by * TH;
    const int tid = threadIdx.x;       // 0..255
    const int txx = tid & 31;          // x-group (4 px each)
    const int ty  = tid >> 5;          // 0..7
    const int wv  = tid >> 6;          // wave 0..3
    const int ln  = tid & 63;          // lane 0..63

    const float* p00 = pred + ((size_t)(0 * BB + b) * 2 + 0) * HW;
    const float* p01 = p00 + HW;
    const float* p10 = pred + ((size_t)(1 * BB + b) * 2 + 0) * HW;
    const float* p11 = p10 + HW;
    const float* q0  = diss + ((size_t)b * 2 + 0) * HW;
    const float* q1  = q0 + HW;

    // ---- stage 0: DMA all six 16x128 tiles into LDS ----
    // 48 chunks of 1 KB (2 rows each); wave wv issues plane-row-pairs
    // rp = wv and wv+4 for each plane: 12 instructions/wave, 0 VGPRs held.
    // Per lane: global = row (2rp + ln>>5), col (ln&31)*4 floats;
    // LDS dest base is uniform, lane i writes base + i*16 -> same layout.
    {
        const int r0  = 2 * wv + (ln >> 5);        // h=0 row within plane pair
        const int r1  = r0 + 8;                    // h=1
        const int col = (ln & 31) << 2;            // float index
        const size_t g0 = (size_t)(y0 + r0) * WW + x0 + col;
        const size_t g1 = (size_t)(y0 + r1) * WW + x0 + col;
        #pragma unroll
        for (int pl = 0; pl < 6; ++pl) {
            const float* pp = (pl == 0) ? p00 : (pl == 1) ? p01 :
                              (pl == 2) ? p10 : (pl == 3) ? p11 :
                              (pl == 4) ? q0  : q1;          // compile-time select
            async16(pp + g0, &planes[pl][2 * wv][0]);
            async16(pp + g1, &planes[pl][2 * wv + 8][0]);
        }
    }

    // ---- stage 1: target halo -> LDS bytes, batch-issued loads ----
    const int* tgt_b = target + (size_t)b * HW;
    int4 iv[3]; int rr[3], mm[3];
    bool act[3], mainp[3], rowin[3];
    #pragma unroll
    for (int i = 0; i < 3; ++i) {
        const int ch = tid + 256 * i;
        const bool a = ch < NCHUNK;
        const int chc = a ? ch : 0;
        const int r = chc / 34;
        const int m = chc - r * 34;
        const int gy  = y0 - 3 + r;
        const int gxb = x0 - 4 + 4 * m;
        const bool ri = (gy >= 0) && (gy < HH);
        const bool fp = a && ri && (gxb >= 0) && (gxb + 3 < WW);
        act[i] = a; rr[i] = r; mm[i] = m; rowin[i] = ri; mainp[i] = fp;
        const int gyc  = ri ? gy  : 0;
        const int gxbc = fp ? gxb : 0;
        iv[i] = *(const int4*)(tgt_b + (size_t)gyc * WW + gxbc); // always safe
    }
    #pragma unroll
    for (int i = 0; i < 3; ++i) {
        if (!act[i]) continue;
        unsigned v = 0u;
        if (mainp[i]) {
            v = (unsigned)(iv[i].x & 0xff)
              | ((unsigned)(iv[i].y & 0xff) << 8)
              | ((unsigned)(iv[i].z & 0xff) << 16)
              | ((unsigned)(iv[i].w & 0xff) << 24);
        } else if (rowin[i]) {
            const int gy  = y0 - 3 + rr[i];
            const int gxb = x0 - 4 + 4 * mm[i];
            #pragma unroll
            for (int j = 0; j < 4; ++j) {
                const int gxj = gxb + j;
                if (gxj >= 0 && gxj < WW)
                    v |= (unsigned)(tgt_b[(size_t)gy * WW + gxj] & 0xff) << (8 * j);
            }
        }
        *(unsigned*)&tile[rr[i]][4 * mm[i]] = v;
    }
    // barrier drains vmcnt(0): all DMA'd planes + target staging complete.
    __syncthreads();

    // ---- stage 2: horizontal sums, SWAR on packed bytes (max 7 < 256) ----
    // h5[r][x] = stored cols x+2..x+6 ; h7[r][x] = stored cols x+1..x+7
    for (int g = tid; g < HALO_H * 32; g += 256) {
        int r  = g >> 5;
        int xg = (g & 31) << 2;
        unsigned c0 = *(const unsigned*)&tile[r][xg];       // stored x..x+3
        unsigned c1 = *(const unsigned*)&tile[r][xg + 4];   // x+4..x+7
        unsigned c2 = *(const unsigned*)&tile[r][xg + 8];   // x+8..x+11
        unsigned A1 = (c0 >> 8)  | (c1 << 24);  // P(x+1)
        unsigned A2 = (c0 >> 16) | (c1 << 16);  // P(x+2)
        unsigned A3 = (c0 >> 24) | (c1 << 8);   // P(x+3)
        unsigned A5 = (c1 >> 8)  | (c2 << 24);  // P(x+5)
        unsigned A6 = (c1 >> 16) | (c2 << 16);  // P(x+6)
        unsigned A7 = (c1 >> 24) | (c2 << 8);   // P(x+7)
        unsigned v5 = A2 + A3 + c1 + A5 + A6;   // bytes <= 5
        unsigned v7 = v5 + A1 + A7;             // bytes <= 7
        *(unsigned*)&h5[r][xg] = v5;
        *(unsigned*)&h7[r][xg] = v7;
    }
    __syncthreads();

    // ---- stage 3: fused per-pixel terms; big data now read from LDS ----
    float sf0=0.f, se0=0.f, si0=0.f, sp0=0.f;   // sp = sum of p1
    float sf1=0.f, se1=0.f, si1=0.f, sp1=0.f;
    float sf2=0.f, se2=0.f, si2=0.f, sd1=0.f;   // sd1 = sum of d1
    float st = 0.f;                             // sum of t (shared U part)

    const int x = txx * 4;                      // float/byte index in tile

    const unsigned t4a   = *(const unsigned*)&tile[ty + 3][x + 4];
    const unsigned cnt4a = *(const unsigned*)&tile[ty    ][x + 4]
                         + *(const unsigned*)&tile[ty + 6][x + 4]
                         + *(const unsigned*)&h5[ty + 1][x]
                         + *(const unsigned*)&h5[ty + 2][x]
                         + *(const unsigned*)&h7[ty + 3][x]
                         + *(const unsigned*)&h5[ty + 4][x]
                         + *(const unsigned*)&h5[ty + 5][x];
    const unsigned t4b   = *(const unsigned*)&tile[ty + 11][x + 4];
    const unsigned cnt4b = *(const unsigned*)&tile[ty +  8][x + 4]
                         + *(const unsigned*)&tile[ty + 14][x + 4]
                         + *(const unsigned*)&h5[ty +  9][x]
                         + *(const unsigned*)&h5[ty + 10][x]
                         + *(const unsigned*)&h7[ty + 11][x]
                         + *(const unsigned*)&h5[ty + 12][x]
                         + *(const unsigned*)&h5[ty + 13][x];

    auto half = [&](unsigned t4, unsigned cnt4, int row) {
        // conflict-free ds_read_b128: wave reads 2 rows x 32 x 16B = 1 KB
        const float4 v00 = *(const float4*)&planes[0][row][x];
        const float4 v01 = *(const float4*)&planes[1][row][x];
        const float4 v10 = *(const float4*)&planes[2][row][x];
        const float4 v11 = *(const float4*)&planes[3][row][x];
        const float4 w0  = *(const float4*)&planes[4][row][x];
        const float4 w1  = *(const float4*)&planes[5][row][x];
        #pragma unroll
        for (int j = 0; j < 4; ++j) {
            const unsigned tb = (t4 >> (8 * j)) & 0xffu;
            const float t  = (float)tb;
            const float at = fabsf(t - (float)((cnt4 >> (8 * j)) & 0xffu) * (1.0f / 29.0f));
            st += t;
            {   // image 0 (softmax of 2 channels)
                float a0 = ((const float*)&v00)[j], a1 = ((const float*)&v01)[j];
                float p1v = __builtin_amdgcn_rcpf(1.0f + __expf(a0 - a1));
                float pt  = (tb != 0u) ? p1v : 1.0f - p1v;
                float lp  = __logf(pt + 1e-10f);
                sf0 -= lp; se0 -= lp * at; si0 += p1v * t; sp0 += p1v;
            }
            {   // image 1
                float a0 = ((const float*)&v10)[j], a1 = ((const float*)&v11)[j];
                float p1v = __builtin_amdgcn_rcpf(1.0f + __expf(a0 - a1));
                float pt  = (tb != 0u) ? p1v : 1.0f - p1v;
                float lp  = __logf(pt + 1e-10f);
                sf1 -= lp; se1 -= lp * at; si1 += p1v * t; sp1 += p1v;
            }
            {   // Diss (raw probs)
                float d0 = ((const float*)&w0)[j], d1 = ((const float*)&w1)[j];
                float pt = (tb != 0u) ? d1 : d0;
                float lp = __logf(pt + 1e-10f);
                sf2 -= lp; se2 -= lp * at; si2 += d1 * t; sd1 += d1;
            }
        }
    };
    half(t4a, cnt4a, ty);
    half(t4b, cnt4b, ty + 8);

    // ---- stage 4: block reduction -> 12 f64 atomics ----
    float vals[12] = {sf0,se0,si0,sp0+st, sf1,se1,si1,sp1+st, sf2,se2,si2,sd1+st};
    #pragma unroll
    for (int j = 0; j < 12; ++j) {
        float v = vals[j];
        #pragma unroll
        for (int s = 32; s > 0; s >>= 1) v += __shfl_down(v, s, 64);
        vals[j] = v;
    }
    const int wave = tid >> 6;
    const int lane = tid & 63;
    if (lane == 0) {
        #pragma unroll
        for (int j = 0; j < 12; ++j) red[wave][j] = vals[j];
    }
    __syncthreads();
    if (tid < 12) {
        double s = (double)red[0][tid] + (double)red[1][tid]
                 + (double)red[2][tid] + (double)red[3][tid];
        const int img  = tid >> 2;
        const int what = tid & 3;
        int slot;
        if      (what == 0) slot = 0;
        else if (what == 1) slot = 1;
        else if (what == 2) slot = 2 + b;
        else                slot = 10 + b;
        const int copy = (by * 8 + bx) & (NCOPY - 1);
        unsafeAtomicAdd(acc + (size_t)copy * CSTRIDE + (img * NSLOT + slot), s);
    }
}

__global__ __launch_bounds__(256)
void finalize_kernel(const double* __restrict__ acc,
                     const float*  __restrict__ diff,
                     const float*  __restrict__ sigma,
                     float*        __restrict__ out)
{
    __shared__ double ssum[54];
    const int t = threadIdx.x;
    if (t < 216) {
        const int slot_lin = t >> 2;   // 0..53 = img*18+slot
        const int part     = t & 3;    // 16 copies each
        const double* p = acc + slot_lin + (size_t)part * 16 * CSTRIDE;
        double s = 0.0;
        #pragma unroll
        for (int j = 0; j < 16; ++j) s += p[(size_t)j * CSTRIDE];
        s += __shfl_down(s, 1, 64);
        s += __shfl_down(s, 2, 64);
        if (part == 0) ssum[slot_lin] = s;
    }
    __syncthreads();
    if (t == 0) {
        const double sig0 = (double)sigma[0] * (double)sigma[0];
        const double sig1 = (double)sigma[1] * (double)sigma[1];
        const double sig2 = (double)sigma[2] * (double)sigma[2];
        const double inv  = 1.0 / (double)((size_t)BB * HW);
        double loss = 0.0;
        for (int i = 0; i < 3; ++i) {
            const double* A = ssum + i * NSLOT;
            double focal = A[0] * inv;
            double edge  = A[1] * inv;
            double dsum  = 0.0;
            for (int b = 0; b < BB; ++b)
                dsum += 2.0 * A[2 + b] / (A[10 + b] + 1e-10);
            double dice = 1.0 - dsum / (double)BB;
            loss += focal / sig0 + dice / sig1 + edge / sig2;
        }
        loss += (double)diff[0];
        loss += 0.5 * (log(sig0) + log(sig1) + log(sig2));
        out[0] = (float)loss;
    }
}

extern "C" void kernel_launch(void* const* d_in, const int* in_sizes, int n_in,
                              void* d_out, int out_size, void* d_ws, size_t ws_size,
                              hipStream_t stream)
{
    const float* pred   = (const float*)d_in[0]; // (2,8,2,1024,1024)
    const float* diss   = (const float*)d_in[1]; // (1,8,2,1024,1024)
    const int*   target = (const int*)  d_in[2]; // (8,1024,1024)
    const float* diff   = (const float*)d_in[3];
    const float* sigma  = (const float*)d_in[4];
    double* acc = (double*)d_ws;

    (void)hipMemsetAsync(d_ws, 0, (size_t)NCOPY * CSTRIDE * sizeof(double), stream);

    dim3 grid(WW / TW, HH / TH, BB);   // (8, 64, 8)
    loss_main<<<grid, 256, 0, stream>>>(pred, diss, target, acc);
    finalize_kernel<<<1, 256, 0, stream>>>(acc, diff, sigma, (float*)d_out);
}